// Round 1
// 770.753 us; speedup vs baseline: 1.2007x; 1.2007x over previous
//
#include <hip/hip_runtime.h>
#include <stdint.h>
#include <math.h>

#define B_  2
#define S_  2048
#define D_  4096
#define H_  32
#define KV_ 8
#define HD_ 128
#define M_  (B_ * S_)   // 4096 rows of the flattened token matrix

typedef unsigned short u16;
typedef unsigned int   u32;

// ---------- bf16 helpers ----------
__device__ __forceinline__ float bf2f(u16 u) {
  union { u32 i; float f; } x; x.i = ((u32)u) << 16; return x.f;
}
__device__ __forceinline__ u16 f2bf(float f) {
  union { float f; u32 i; } x; x.f = f;
  u32 r = x.i + 0x7fffu + ((x.i >> 16) & 1u);   // RNE
  return (u16)(r >> 16);
}
// pack two f32 -> two bf16 (round-half-up) in ONE v_perm
__device__ __forceinline__ u32 pack_bf16_rh(float hi, float lo) {
  union { float f; u32 i; } a, c; a.f = hi; c.f = lo;
  return __builtin_amdgcn_perm(a.i + 0x8000u, c.i + 0x8000u, 0x07060302u);
}

typedef __attribute__((ext_vector_type(8))) short bf16x8;
typedef __attribute__((ext_vector_type(4))) float f32x4;

__device__ __forceinline__ void async_cp16(const void* g, void* l) {
  __builtin_amdgcn_global_load_lds(
      (const __attribute__((address_space(1))) u32*)g,
      (__attribute__((address_space(3))) u32*)l, 16, 0, 0);
}

#define SBAR   asm volatile("s_barrier" ::: "memory")
#define WAITL0 asm volatile("s_waitcnt lgkmcnt(0)" ::: "memory")
#define WAITV(n) asm volatile("s_waitcnt vmcnt(" #n ")" ::: "memory")

// ---------- fp32 -> bf16 convert ----------
__global__ void k_f32_to_bf16(const float* __restrict__ src, u16* __restrict__ dst, int n) {
  int i = (blockIdx.x * 256 + threadIdx.x) * 4;
  if (i >= n) return;
  float4 v = *(const float4*)(src + i);
  ushort4 o;
  o.x = f2bf(v.x); o.y = f2bf(v.y); o.z = f2bf(v.z); o.w = f2bf(v.w);
  *(ushort4*)(dst + i) = o;
}

// ---------- 256x256 8-phase GEMM: C[M,N] = A[M,K] * B[N,K]^T (bf16 in, OutT out) ----
// Port of the verified 8-phase template: BK=64, 8 waves (2Mx4N), double-buffered
// 128 KiB LDS, 8-elem-block XOR swizzle (linear LDS dest, pre-swizzled global src,
// swizzled ds_read), 1 half-tile staged per phase, counted vmcnt(4) at ph4/ph8 only,
// raw s_barrier (no vmcnt-draining __syncthreads), setprio(1) around MFMA cluster.
template <typename OutT>
__global__ __launch_bounds__(512, 2) void k_gemm256_bt(const u16* __restrict__ A,
                                                       const u16* __restrict__ Bm,
                                                       OutT* __restrict__ C,
                                                       int M, int N, int K) {
  __shared__ __align__(16) u16 As[2][256 * 64];   // 64 KiB
  __shared__ __align__(16) u16 Bs[2][256 * 64];   // 64 KiB
  const int t = threadIdx.x;
  const int l = t & 63;
  const int w = t >> 6;
  const int wr = w >> 2, wc = w & 3;              // 2x4 waves; per-wave 128x64 output
  const int quad = l >> 4, lm = l & 15, l7 = l & 7;
  const int m0 = blockIdx.y * 256, n0 = blockIdx.x * 256;

  // staging: thread t covers phys row srow(+j*64,+h*128), phys col-block (t&7).
  // logical col block = phys ^ (row&7); row&7 == (t>>3)&7 for all j,h.
  const int srow = t >> 3;
  const int scb  = (t & 7) ^ (srow & 7);
  const u16* srcA = A  + (size_t)(m0 + srow) * K + scb * 8;
  const u16* srcB = Bm + (size_t)(n0 + srow) * K + scb * 8;
  u16* dA = &As[0][0] + t * 8;
  u16* dB = &Bs[0][0] + t * 8;
  const size_t row64 = (size_t)64 * K;

  // ds-read bases (u16 indices); phys block = (ks*4+quad) ^ (row&7), row&7 == l7
  const int rowA = (wr * 128 + lm) * 64;
  const int rowB = (wc * 64 + lm) * 64;
  const int kq0 = ((0 * 4 + quad) ^ l7) * 8;
  const int kq1 = ((1 * 4 + quad) ^ l7) * 8;
  const u16* As0 = &As[0][0];
  const u16* Bs0 = &Bs[0][0];

  f32x4 acc[8][4];
#pragma unroll
  for (int i2 = 0; i2 < 8; ++i2)
#pragma unroll
    for (int j2 = 0; j2 < 4; ++j2) {
      f32x4 z = {0.f, 0.f, 0.f, 0.f};
      acc[i2][j2] = z;
    }

  auto stgA = [&](int buf, int kt, int h) {
    const u16* s = srcA + (size_t)kt * 64 + (size_t)(h * 128) * K;
    u16* d = dA + buf * 16384 + h * 8192;
    async_cp16(s, d);
    async_cp16(s + row64, d + 4096);
  };
  auto stgB = [&](int buf, int kt, int h) {
    const u16* s = srcB + (size_t)kt * 64 + (size_t)(h * 128) * K;
    u16* d = dB + buf * 16384 + h * 8192;
    async_cp16(s, d);
    async_cp16(s + row64, d + 4096);
  };

  // prologue: K-tile 0 -> buf0 (A+B), B of K-tile 1 -> buf1. A(1) staged in ph1-2.
  stgA(0, 0, 0); stgA(0, 0, 1);
  stgB(0, 0, 0); stgB(0, 0, 1);
  stgB(1, 1, 0); stgB(1, 1, 1);
  WAITV(4);        // force A(0),B(0); leave B(1)'s 4 loads in flight
  SBAR;

  const int iters = K >> 7;                        // 2 K-tiles (K=128) per iteration
  for (int i = 0; i < iters; ++i) {
    const int kt = 2 * i;
    const bool notLast = (i + 1 < iters);
#pragma unroll
    for (int hf = 0; hf < 2; ++hf) {               // buffer parity == K-tile parity
      bf16x8 bfr[4][2];
#pragma unroll
      for (int q = 0; q < 4; ++q) {                // phase = hf*4 + q
        // ---- ds-loads for this phase ----
        if (q == 0) {
#pragma unroll
          for (int fn = 0; fn < 4; ++fn) {
            const int ro = hf * 16384 + rowB + fn * 1024;
            bfr[fn][0] = *(const bf16x8*)&Bs0[ro + kq0];
            bfr[fn][1] = *(const bf16x8*)&Bs0[ro + kq1];
          }
        }
        bf16x8 af[2][2];
#pragma unroll
        for (int fo = 0; fo < 2; ++fo) {
          const int ro = hf * 16384 + rowA + (2 * q + fo) * 1024;
          af[fo][0] = *(const bf16x8*)&As0[ro + kq0];
          af[fo][1] = *(const bf16x8*)&As0[ro + kq1];
        }
        // ---- stage one half-tile (schedule: regions written only after last read) ----
        if (hf == 0) {
          if (q == 0)      stgA(1, kt + 1, 0);     // bufA1 free (read last iter ph5-8)
          else if (q == 1) stgA(1, kt + 1, 1);
          else if (q == 2) { if (notLast) stgB(0, kt + 2, 0); }  // bufB0 free after ph1
          else {
            if (notLast) { stgB(0, kt + 2, 1); WAITV(4); }  // forces A(kt+1)+B(kt+1)
            else WAITV(0);
          }
        } else if (notLast) {
          if (q == 0)      stgA(0, kt + 2, 0);     // bufA0 free after ph4
          else if (q == 1) stgA(0, kt + 2, 1);
          else if (q == 2) stgB(1, kt + 3, 0);     // bufB1 free after ph5
          else { stgB(1, kt + 3, 1); WAITV(4); }   // forces A(kt+2)+B(kt+2)
        }
        SBAR;
        WAITL0;
        __builtin_amdgcn_s_setprio(1);
#pragma unroll
        for (int fo = 0; fo < 2; ++fo)
#pragma unroll
          for (int fn = 0; fn < 4; ++fn)
            acc[2 * q + fo][fn] = __builtin_amdgcn_mfma_f32_16x16x32_bf16(
                af[fo][0], bfr[fn][0], acc[2 * q + fo][fn], 0, 0, 0);
#pragma unroll
        for (int fo = 0; fo < 2; ++fo)
#pragma unroll
          for (int fn = 0; fn < 4; ++fn)
            acc[2 * q + fo][fn] = __builtin_amdgcn_mfma_f32_16x16x32_bf16(
                af[fo][1], bfr[fn][1], acc[2 * q + fo][fn], 0, 0, 0);
        __builtin_amdgcn_s_setprio(0);
        SBAR;
      }
    }
  }

  // ---- epilogue ----
#pragma unroll
  for (int fm = 0; fm < 8; ++fm) {
    const int row = m0 + wr * 128 + fm * 16 + quad * 4;
#pragma unroll
    for (int fn = 0; fn < 4; ++fn) {
      const int col = n0 + wc * 64 + fn * 16 + lm;
#pragma unroll
      for (int r = 0; r < 4; ++r) {
        float v = acc[fm][fn][r];
        if constexpr (sizeof(OutT) == 2)
          C[(size_t)(row + r) * N + col] = (OutT)f2bf(v);
        else
          C[(size_t)(row + r) * N + col] = v;
      }
    }
  }
}

// ---------- RoPE: Q [m][H*128], K inside merged KV [m][2048] (first 1024) ----------
__global__ __launch_bounds__(256) void k_rope(u16* __restrict__ Q, u16* __restrict__ Km,
                                              const int* __restrict__ pos_ids) {
  const int t = threadIdx.x;
  const int bs = blockIdx.x * 4 + (t >> 6);
  const int d = t & 63;
  const int hg = blockIdx.y;             // 0..9 -> heads hg*4..hg*4+3 (32 Q + 8 K)
  const float pos = (float)pos_ids[bs];
  const float ang = pos * expf(-(float)d * 0.1439115683121279f);
  float sn, cs;
  sincosf(ang, &sn, &cs);
#pragma unroll
  for (int j = 0; j < 4; j++) {
    const int hh = hg * 4 + j;
    u16* p = (hh < H_) ? (Q + (size_t)bs * (H_ * HD_) + hh * HD_)
                       : (Km + (size_t)bs * 2048 + (hh - H_) * HD_);
    const float x1 = bf2f(p[d]);
    const float x2 = bf2f(p[d + 64]);
    p[d]      = f2bf(x1 * cs - x2 * sn);
    p[d + 64] = f2bf(x2 * cs + x1 * sn);
  }
}

// ---------- V transpose: V inside merged KV [m][2048] (last 1024) -> Vt [B][KV][HD][S] ----------
__global__ __launch_bounds__(256) void k_transpose_v(const u16* __restrict__ KVb,
                                                     u16* __restrict__ Vt) {
  __shared__ u16 tile[64][136];
  const int s0 = blockIdx.x * 64;
  const int kvh = blockIdx.y & 7, b = blockIdx.y >> 3;
  const int t = threadIdx.x;
  const int sl = t >> 2, d0 = (t & 3) * 32;
  const u16* src = KVb + (size_t)(b * S_ + s0 + sl) * 2048 + 1024 + kvh * 128 + d0;
#pragma unroll
  for (int j = 0; j < 4; j++)
    *(uint4*)&tile[sl][d0 + j * 8] = *(const uint4*)(src + j * 8);
  __syncthreads();
  const int lt = t & 63, wv = t >> 6;
  u16* dst = Vt + ((size_t)(b * KV_ + kvh) * HD_) * (size_t)S_ + s0 + lt;
#pragma unroll
  for (int i = 0; i < 32; i++) {
    const int d = i * 4 + wv;
    dst[(size_t)d * S_] = tile[lt][d];
  }
}

// ---------- MFMA flash attention v2 ----------
__global__ __launch_bounds__(256, 2) void k_attn_mfma(const u16* __restrict__ Q,
                                                      const u16* __restrict__ KVb,
                                                      const u16* __restrict__ Vt,
                                                      u16* __restrict__ O) {
  __shared__ __align__(16) u16 Ks[2][64 * 128];   // [kv][hd], 16B-block xor-swizzled
  __shared__ __align__(16) u16 Vs[2][128 * 64];   // [d][kv]
  __shared__ __align__(16) u16 Ps[128 * 64];      // [q][kv]
  const int qt = (S_ / 128 - 1) - blockIdx.x;     // longest strips first
  const int h = blockIdx.y, b = blockIdx.z;
  const int kvh = h >> 2;                         // n_rep = 4
  const int t = threadIdx.x;
  const int w = t >> 6, l = t & 63;
  const int quad = l >> 4, lm = l & 15, l7 = l & 7;
  const int q0 = qt * 128, wq = w * 32;

  bf16x8 qf[2][4];
#pragma unroll
  for (int nt = 0; nt < 2; nt++)
#pragma unroll
    for (int ks = 0; ks < 4; ks++) {
      const int qrow = q0 + wq + nt * 16 + lm;
      qf[nt][ks] = *(const bf16x8*)(Q + (size_t)(b * S_ + qrow) * (H_ * HD_)
                                    + h * HD_ + ks * 32 + quad * 8);
    }

  const u16* kSrc[4]; const u16* vSrc[4];
  int dstOff[4];
#pragma unroll
  for (int j = 0; j < 4; j++) {
    const int c = w * 4 + j;
    kSrc[j] = KVb + (size_t)(b * S_ + c * 4 + (l >> 4)) * 2048 + kvh * 128
              + 8 * ((l & 15) ^ ((c & 1) * 4 + (l >> 4)));
    vSrc[j] = Vt + ((size_t)(b * KV_ + kvh) * HD_ + c * 8 + (l >> 3)) * (size_t)S_
              + 8 * ((l & 7) ^ (l >> 3));
    dstOff[j] = c * 512 + l * 8;
  }

  f32x4 Oa[8][2];
#pragma unroll
  for (int dt = 0; dt < 8; dt++)
#pragma unroll
    for (int nt = 0; nt < 2; nt++) {
      f32x4 z = {0.f, 0.f, 0.f, 0.f};
      Oa[dt][nt] = z;
    }
  float lsum[2] = {0.f, 0.f};

  const int nTiles = (qt + 1) * 2;

#pragma unroll
  for (int j = 0; j < 4; j++) {
    async_cp16(kSrc[j], &Ks[0][dstOff[j]]);
    async_cp16(vSrc[j], &Vs[0][dstOff[j]]);
  }

  for (int tile = 0; tile < nTiles; tile++) {
    const int cur = tile & 1;
    __builtin_amdgcn_s_waitcnt(0);
    __syncthreads();
    if (tile + 1 < nTiles) {
      const size_t kAdv = (size_t)(tile + 1) * 64 * 2048;
      const int vAdv = (tile + 1) * 64;
      const int nxt = cur ^ 1;
#pragma unroll
      for (int j = 0; j < 4; j++) {
        async_cp16(kSrc[j] + kAdv, &Ks[nxt][dstOff[j]]);
        async_cp16(vSrc[j] + vAdv, &Vs[nxt][dstOff[j]]);
      }
    }
    const u16* KsC = Ks[cur];
    const u16* VsC = Vs[cur];

    f32x4 st[4][2];
#pragma unroll
    for (int kvt = 0; kvt < 4; kvt++)
#pragma unroll
      for (int nt = 0; nt < 2; nt++) {
        f32x4 z = {0.f, 0.f, 0.f, 0.f};
        st[kvt][nt] = z;
      }
#pragma unroll
    for (int ks = 0; ks < 4; ks++) {
      bf16x8 kf[4];
#pragma unroll
      for (int kvt = 0; kvt < 4; kvt++)
        kf[kvt] = *(const bf16x8*)&KsC[(kvt * 16 + lm) * 128 + ((ks * 4 + quad) ^ l7) * 8];
#pragma unroll
      for (int kvt = 0; kvt < 4; kvt++) {
        st[kvt][0] = __builtin_amdgcn_mfma_f32_16x16x32_bf16(kf[kvt], qf[0][ks], st[kvt][0], 0, 0, 0);
        st[kvt][1] = __builtin_amdgcn_mfma_f32_16x16x32_bf16(kf[kvt], qf[1][ks], st[kvt][1], 0, 0, 0);
      }
    }

    const int kt0 = tile * 64;
    const bool diag = (tile >= nTiles - 2);
#pragma unroll
    for (int nt = 0; nt < 2; nt++) {
      const int qg = q0 + wq + nt * 16 + lm;
      const int prow = (wq + nt * 16 + lm) * 64;
#pragma unroll
      for (int kvt = 0; kvt < 4; kvt++) {
        float p[4];
#pragma unroll
        for (int r = 0; r < 4; r++) {
          float e = __expf(st[kvt][nt][r] * 0.08838834764831845f);
          if (diag) {
            const int kg = kt0 + kvt * 16 + quad * 4 + r;
            e = (kg <= qg) ? e : 0.f;
          }
          p[r] = e;
          lsum[nt] += e;
        }
        uint2 pk;
        pk.x = pack_bf16_rh(p[1], p[0]);
        pk.y = pack_bf16_rh(p[3], p[2]);
        const int pb = (2 * kvt + (quad >> 1)) ^ l7;
        *(uint2*)&Ps[prow + pb * 8 + (quad & 1) * 4] = pk;
      }
    }

#pragma unroll
    for (int ks2 = 0; ks2 < 2; ks2++) {
      const int pboff = ((ks2 * 4 + quad) ^ l7) * 8;
      bf16x8 pf0 = *(const bf16x8*)&Ps[(wq + lm) * 64 + pboff];
      bf16x8 pf1 = *(const bf16x8*)&Ps[(wq + 16 + lm) * 64 + pboff];
#pragma unroll
      for (int dt = 0; dt < 8; dt++) {
        bf16x8 vf = *(const bf16x8*)&VsC[(dt * 16 + lm) * 64 + pboff];
        Oa[dt][0] = __builtin_amdgcn_mfma_f32_16x16x32_bf16(vf, pf0, Oa[dt][0], 0, 0, 0);
        Oa[dt][1] = __builtin_amdgcn_mfma_f32_16x16x32_bf16(vf, pf1, Oa[dt][1], 0, 0, 0);
      }
    }
  }

#pragma unroll
  for (int nt = 0; nt < 2; nt++) {
    lsum[nt] += __shfl_xor(lsum[nt], 16);
    lsum[nt] += __shfl_xor(lsum[nt], 32);
  }
#pragma unroll
  for (int nt = 0; nt < 2; nt++) {
    const float inv = 1.f / lsum[nt];
    const int qg = q0 + wq + nt * 16 + lm;
    u16* obase = O + (size_t)(b * S_ + qg) * (H_ * HD_) + h * HD_ + quad * 4;
#pragma unroll
    for (int dt = 0; dt < 8; dt++) {
      uint2 pk;
      pk.x = pack_bf16_rh(Oa[dt][nt][1] * inv, Oa[dt][nt][0] * inv);
      pk.y = pack_bf16_rh(Oa[dt][nt][3] * inv, Oa[dt][nt][2] * inv);
      *(uint2*)(obase + dt * 16) = pk;
    }
  }
}

// ---------- launch ----------
extern "C" void kernel_launch(void* const* d_in, const int* in_sizes, int n_in,
                              void* d_out, int out_size, void* d_ws, size_t ws_size,
                              hipStream_t stream) {
  const float* hs = (const float*)d_in[0];
  const float* Wq = (const float*)d_in[1];
  const float* Wk = (const float*)d_in[2];
  const float* Wv = (const float*)d_in[3];
  const float* Wo = (const float*)d_in[4];
  const int*  pos = (const int*)d_in[5];
  float* out = (float*)d_out;

  u16* hbuf = (u16*)d_ws;                           // M*D   (hidden; later AO)
  u16* wbuf = hbuf + (size_t)M_ * D_;               // Wq bf16; later Wo bf16
  u16* wkvb = wbuf + (size_t)(H_ * HD_) * D_;       // [Wk(1024) ; Wv(1024)] x D; later Vt
  u16* Qb   = wkvb + (size_t)2048 * D_;             // M x 4096
  u16* KVb  = Qb   + (size_t)M_ * (H_ * HD_);       // M x 2048 merged [K|V]
  u16* Vt   = wkvb;                                 // aliases weights after KV GEMM

  const int nHid = M_ * D_;
  const int nWq  = H_ * HD_ * D_;
  const int nWk  = KV_ * HD_ * D_;

  k_f32_to_bf16<<<nHid / 1024, 256, 0, stream>>>(hs, hbuf, nHid);
  k_f32_to_bf16<<<nWq  / 1024, 256, 0, stream>>>(Wq, wbuf, nWq);
  k_f32_to_bf16<<<nWk  / 1024, 256, 0, stream>>>(Wk, wkvb, nWk);
  k_f32_to_bf16<<<nWk  / 1024, 256, 0, stream>>>(Wv, wkvb + (size_t)1024 * D_, nWk);

  dim3 blk(512);
  k_gemm256_bt<u16><<<dim3((H_ * HD_) / 256, M_ / 256), blk, 0, stream>>>(hbuf, wbuf, Qb,  M_, H_ * HD_, D_);
  k_gemm256_bt<u16><<<dim3(2048 / 256, M_ / 256),       blk, 0, stream>>>(hbuf, wkvb, KVb, M_, 2048,     D_);

  k_f32_to_bf16<<<nWq / 1024, 256, 0, stream>>>(Wo, wbuf, nWq);

  k_rope<<<dim3(M_ / 4, (H_ + KV_) / 4), 256, 0, stream>>>(Qb, KVb, pos);

  k_transpose_v<<<dim3(S_ / 64, B_ * KV_), 256, 0, stream>>>(KVb, Vt);

  k_attn_mfma<<<dim3(S_ / 128, H_, B_), 256, 0, stream>>>(Qb, KVb, Vt, hbuf);

  k_gemm256_bt<float><<<dim3(D_ / 256, M_ / 256), blk, 0, stream>>>(hbuf, wbuf, out, M_, D_, H_ * HD_);
}